// Round 4
// baseline (17756.792 us; speedup 1.0000x reference)
//
#include <hip/hip_runtime.h>
#include <hip/hip_bf16.h>

// RecurrentAE on MI355X — round 8.
//  - r7 post-mortem: enc and dec both ~9.7 µs/step regardless of compute -> the step IS the
//    sync chain (2 serialized LLC hops + full L2 inv + cold refill). enc FETCH 599MB shows
//    the per-step inv also evicts read-only x from L2.
//  - NEW: NO invalidates, NO leader/epoch. h is read DIRECTLY from the LLC via agent-scope
//    atomic u64 loads (sc1 -> bypass L0+L2, read coherence point). Producers write-through
//    (agent atomic stores) and drain (syncthreads => vmcnt(0)) before arriving, so LLC is
//    the single source of truth. Barrier = single hop: every WG's thread0 polls the 16
//    spread counters. (r5's all-poll failed only because of its per-WG L2 inv — removed.)
//  - Keep r7: 32x32x16 MFMA, 8-wave K-split (partials in sGa/sGb), rolling A-prefetch,
//    16 dedicated out-WGs (grid 144), weights/x via plain cached loads (now L2-stable).

#define B_ 128
#define S_ 512
#define F_ 128
#define L_ 1024
#define U_ 8
#define NWG_E 128
#define NWG_D 144          // 128 gate WGs + 16 out WGs

typedef __bf16 bf16x8 __attribute__((ext_vector_type(8)));
typedef float  f32x4  __attribute__((ext_vector_type(4)));
typedef float  f32x16 __attribute__((ext_vector_type(16)));
typedef int    i32x4  __attribute__((ext_vector_type(4)));
typedef unsigned long long u64;

union pk2 { unsigned u; __bf16 h[2]; };
union fu  { float f; unsigned u; };
union b8  { u64 q[2]; bf16x8 v; };

#define MFMA32(a, b, c) __builtin_amdgcn_mfma_f32_32x32x16_bf16(a, b, c, 0, 0, 0)
#define Z16 f32x16{0.f,0.f,0.f,0.f,0.f,0.f,0.f,0.f,0.f,0.f,0.f,0.f,0.f,0.f,0.f,0.f}

// agent-scope (device) load: {sc1,sc0}=10 -> bypass L0+L2, read LLC (the coherence point)
__device__ __forceinline__ bf16x8 ld_h(const __bf16* p) {
    b8 u;
    u.q[0] = __hip_atomic_load((const u64*)p,     __ATOMIC_RELAXED, __HIP_MEMORY_SCOPE_AGENT);
    u.q[1] = __hip_atomic_load((const u64*)p + 1, __ATOMIC_RELAXED, __HIP_MEMORY_SCOPE_AGENT);
    return u.v;
}

// ---------------- workspace layout (bytes) ----------------
#define O_H0   0                          // bf16 [128][1024]
#define O_H1   (256*1024)                 // bf16 [128][1024]
#define O_H32  (512*1024)                 // f32  [128][1024]
#define O_CTR  (1024*1024)                // sync: enc @ +0, dec @ +4096 (1024 u32 each)
#define O_ZERO_END (1024*1024 + 8192)
#define O_XB   O_ZERO_END                 // bf16 [128][512][128] = 16777216
#define O_WEH  (O_XB  + 16777216)         // bf16 [128][32][1024] = 8388608
#define O_WEX  (O_WEH + 8388608)          // bf16 [128][32][128]  = 1048576
#define O_BE   (O_WEX + 1048576)          // f32  [128][32]       = 16384
#define O_WD   (O_BE  + 16384)            // bf16 [128][32][1024] = 8388608
#define O_BD   (O_WD  + 8388608)          // f32  [128][32]       = 16384
#define O_WC   (O_BD  + 16384)            // bf16 [3072][1024]    = 6291456
#define O_WOB  (O_WC  + 6291456)          // bf16 [128][1024]     = 262144
// total ~42 MB

// ---------------- prep kernels ----------------

__global__ void k_xcvt(const float* __restrict__ x, __bf16* __restrict__ xb, int n) {
    int i = blockIdx.x * 256 + threadIdx.x;
    int stride = gridDim.x * 256;
    for (; i < n; i += stride) xb[i] = (__bf16)x[i];
}

__global__ void k_woutb(const float* __restrict__ Wout, __bf16* __restrict__ Wob, int n) {
    int i = blockIdx.x * 256 + threadIdx.x;
    if (i < n) Wob[i] = (__bf16)Wout[i];
}

// encoder pack: 32 cols/WG, 4 per unit {r, z, n_i, n_h}
__global__ void k_pack_enc(const float* __restrict__ Wih, const float* __restrict__ Whh,
                           const float* __restrict__ bih, const float* __restrict__ bhh,
                           __bf16* __restrict__ Weh, __bf16* __restrict__ Wex,
                           float* __restrict__ be) {
    int g = blockIdx.x, tid = threadIdx.x;
    for (int i = tid; i < 32 * 1024; i += 256) {
        int c = i >> 10, k = i & 1023;
        int u = g * U_ + (c >> 2), gate = c & 3;
        float v = 0.f;
        if (gate == 0)      v = Whh[(size_t)u * 1024 + k];
        else if (gate == 1) v = Whh[(size_t)(1024 + u) * 1024 + k];
        else if (gate == 3) v = Whh[(size_t)(2048 + u) * 1024 + k];
        Weh[((size_t)g * 32 + c) * 1024 + k] = (__bf16)v;
    }
    for (int i = tid; i < 32 * 128; i += 256) {
        int c = i >> 7, k = i & 127;
        int u = g * U_ + (c >> 2), gate = c & 3;
        float v = 0.f;
        if (gate == 0)      v = Wih[(size_t)u * 128 + k];
        else if (gate == 1) v = Wih[(size_t)(1024 + u) * 128 + k];
        else if (gate == 2) v = Wih[(size_t)(2048 + u) * 128 + k];
        Wex[((size_t)g * 32 + c) * 128 + k] = (__bf16)v;
    }
    if (tid < 32) {
        int c = tid, u = g * U_ + (c >> 2), gate = c & 3;
        float v;
        if (gate == 0)      v = bih[u] + bhh[u];
        else if (gate == 1) v = bih[1024 + u] + bhh[1024 + u];
        else if (gate == 2) v = bih[2048 + u];
        else                v = bhh[2048 + u];
        be[g * 32 + c] = v;
    }
}

// W_comb = W_ih_d @ W_out
__global__ void k_wcomb(const float* __restrict__ Wihd, const float* __restrict__ Wout,
                        __bf16* __restrict__ Wc) {
    __shared__ float a[8][128];
    int r0 = blockIdx.x * 8, tid = threadIdx.x;
    for (int i = tid; i < 8 * 128; i += 256)
        a[i >> 7][i & 127] = Wihd[(size_t)(r0 + (i >> 7)) * 128 + (i & 127)];
    __syncthreads();
    for (int j = tid; j < 1024; j += 256) {
        float acc[8] = {0, 0, 0, 0, 0, 0, 0, 0};
        for (int f = 0; f < 128; ++f) {
            float w = Wout[(size_t)f * 1024 + j];
#pragma unroll
            for (int r = 0; r < 8; ++r) acc[r] += a[r][f] * w;
        }
        for (int r = 0; r < 8; ++r) Wc[(size_t)(r0 + r) * 1024 + j] = (__bf16)acc[r];
    }
}

// decoder pack: 32 cols/WG {r:Whh+Wc, z:Whh+Wc, n_i:Wc, n_h:Whh}
__global__ void k_pack_dec(const float* __restrict__ Whhd, const __bf16* __restrict__ Wc,
                           const float* __restrict__ Wihd,
                           const float* __restrict__ bihd, const float* __restrict__ bhhd,
                           const float* __restrict__ bout,
                           __bf16* __restrict__ Wd, float* __restrict__ bd) {
    int g = blockIdx.x, tid = threadIdx.x;
    for (int i = tid; i < 32 * 1024; i += 256) {
        int c = i >> 10, k = i & 1023;
        int u = g * U_ + (c >> 2), gate = c & 3;
        float v;
        if (gate == 0)      v = Whhd[(size_t)u * 1024 + k] + (float)Wc[(size_t)u * 1024 + k];
        else if (gate == 1) v = Whhd[(size_t)(1024 + u) * 1024 + k] + (float)Wc[(size_t)(1024 + u) * 1024 + k];
        else if (gate == 2) v = (float)Wc[(size_t)(2048 + u) * 1024 + k];
        else                v = Whhd[(size_t)(2048 + u) * 1024 + k];
        Wd[((size_t)g * 32 + c) * 1024 + k] = (__bf16)v;
    }
    if (tid < 32) {
        int c = tid;
        int u = g * U_ + (c >> 2), gate = c & 3;
        int row = (gate == 0) ? u : (gate == 1) ? (1024 + u) : (2048 + u);
        float v;
        if (gate <= 1) {
            float d = 0.f;
            for (int f = 0; f < 128; ++f) d += Wihd[(size_t)row * 128 + f] * bout[f];
            v = d + bihd[row] + bhhd[row];
        } else if (gate == 2) {
            float d = 0.f;
            for (int f = 0; f < 128; ++f) d += Wihd[(size_t)row * 128 + f] * bout[f];
            v = d + bihd[row];
        } else {
            v = bhhd[row];
        }
        bd[g * 32 + c] = v;
    }
}

// ---------------- barrier: 16 counters (128B apart), single-hop all-poll, NO inv ----------

__device__ __forceinline__ void bar_arrive(unsigned* base, int g) {
    if (threadIdx.x == 0)
        __hip_atomic_fetch_add(base + (g & 15) * 32, 1u,
                               __ATOMIC_RELAXED, __HIP_MEMORY_SCOPE_AGENT);
}

__device__ __forceinline__ void bar_wait(unsigned* base, unsigned tgt) {
    if (threadIdx.x == 0) {
        for (;;) {
            unsigned sum = 0;
#pragma unroll
            for (int j = 0; j < 16; ++j)
                sum += __hip_atomic_load(base + j * 32, __ATOMIC_RELAXED, __HIP_MEMORY_SCOPE_AGENT);
            if (sum >= tgt) break;
            __builtin_amdgcn_s_sleep(1);
        }
    }
    __syncthreads();
}

// ---------------- encoder ----------------
// 8 GEMM waves: wave w (w<4) rows (w&3)*32, K-frags 0..31 -> sGa;
//               wave w+4     same rows,     K-frags 32..63 -> sGb (+ x part, overlapped).
__global__ __launch_bounds__(512, 2) void k_enc(
    const __bf16* __restrict__ xb, const __bf16* __restrict__ Weh,
    const __bf16* __restrict__ Wex, const float* __restrict__ be,
    __bf16* __restrict__ h0, __bf16* __restrict__ h1,
    float* __restrict__ h32, unsigned* __restrict__ ctr) {
    __shared__ __align__(16) __bf16 sWh[32][1032];
    __shared__ __align__(16) __bf16 sWx[32][136];
    __shared__ float sB[32];
    __shared__ __align__(16) float sGa[128][36];
    __shared__ __align__(16) float sGb[128][36];
    const int g = blockIdx.x, tid = threadIdx.x;
    const int lane = tid & 63, wave = tid >> 6;

    for (int i = tid; i < 32 * 128; i += 512) {
        int c = i >> 7, k8 = i & 127;
        *(i32x4*)&sWh[c][k8 * 8] = *(const i32x4*)(Weh + ((size_t)g * 32 + c) * 1024 + k8 * 8);
    }
    for (int i = tid; i < 32 * 16; i += 512) {
        int c = i >> 4, k8 = i & 15;
        *(i32x4*)&sWx[c][k8 * 8] = *(const i32x4*)(Wex + ((size_t)g * 32 + c) * 128 + k8 * 8);
    }
    if (tid < 32) sB[tid] = be[g * 32 + tid];
    __syncthreads();

    const int bcol = lane & 31;
    const int koff = (lane >> 5) * 8;
    const int mrow = (wave & 3) * 32 + bcol;
    const int kb = (wave >> 2) * 32;           // this wave's K-frag base
    const bool up = (wave >= 4);

    bf16x8 xrg[8];
    if (up) {
#pragma unroll
        for (int kt = 0; kt < 8; ++kt) xrg[kt] = *(const bf16x8*)(&sWx[bcol][kt * 16 + koff]);
    }

    const int erow = tid >> 2, pair = tid & 3;
    const int hidx2 = erow * 512 + g * 4 + pair;
    float ha = 0.f, hb = 0.f;

    // x-part of step 0 (upper waves)
    f32x16 accx = Z16;
    if (up) {
        const __bf16* xr = xb + (size_t)mrow * 65536;
#pragma unroll
        for (int kt = 0; kt < 8; ++kt)
            accx = MFMA32(*(const bf16x8*)(xr + kt * 16 + koff), xrg[kt], accx);
    }

    for (int s = 0; s < 512; ++s) {
        const __bf16* hcur = (s & 1) ? h1 : h0;
        __bf16* hnxt = (s & 1) ? h0 : h1;
        {
            f32x16 aA = up ? accx : Z16;
            f32x16 aB = Z16;
            const __bf16* hr = hcur + (size_t)mrow * 1024 + kb * 16;
            bf16x8 af[16];
#pragma unroll
            for (int i = 0; i < 16; ++i) af[i] = ld_h(hr + i * 16 + koff);
#pragma unroll
            for (int i = 0; i < 16; ++i) {
                bf16x8 a = af[i];
                af[i] = ld_h(hr + (16 + i) * 16 + koff);
                const bf16x8 b = *(const bf16x8*)(&sWh[bcol][(kb + i) * 16 + koff]);
                if (i & 1) aB = MFMA32(a, b, aB); else aA = MFMA32(a, b, aA);
            }
#pragma unroll
            for (int i = 0; i < 16; ++i) {
                const bf16x8 b = *(const bf16x8*)(&sWh[bcol][(kb + 16 + i) * 16 + koff]);
                if (i & 1) aB = MFMA32(af[i], b, aB); else aA = MFMA32(af[i], b, aA);
            }
            f32x16 acc = aA + aB;
            // C frag: col = lane&31, row = (r&3) + 8*(r>>2) + 4*(lane>>5)
            int rb = (wave & 3) * 32 + 4 * (lane >> 5);
            float (*sg)[36] = up ? sGb : sGa;
#pragma unroll
            for (int r = 0; r < 16; ++r)
                sg[rb + (r & 3) + 8 * (r >> 2)][bcol] = acc[r];
        }
        __syncthreads();
        {
            f32x4 g0 = *(const f32x4*)&sGa[erow][pair * 8] + *(const f32x4*)&sGb[erow][pair * 8];
            f32x4 g1 = *(const f32x4*)&sGa[erow][pair * 8 + 4] + *(const f32x4*)&sGb[erow][pair * 8 + 4];
            int c0 = pair * 8;
            float r = 1.f / (1.f + __expf(-(g0[0] + sB[c0 + 0])));
            float z = 1.f / (1.f + __expf(-(g0[1] + sB[c0 + 1])));
            float n = tanhf(g0[2] + sB[c0 + 2] + r * (g0[3] + sB[c0 + 3]));
            ha = (1.f - z) * n + z * ha;
            r = 1.f / (1.f + __expf(-(g1[0] + sB[c0 + 4])));
            z = 1.f / (1.f + __expf(-(g1[1] + sB[c0 + 5])));
            n = tanhf(g1[2] + sB[c0 + 6] + r * (g1[3] + sB[c0 + 7]));
            hb = (1.f - z) * n + z * hb;
            pk2 p; p.h[0] = (__bf16)ha; p.h[1] = (__bf16)hb;
            __hip_atomic_store((unsigned*)hnxt + hidx2, p.u, __ATOMIC_RELAXED, __HIP_MEMORY_SCOPE_AGENT);
            if (s == 511) {
                h32[erow * 1024 + g * 8 + pair * 2]     = ha;
                h32[erow * 1024 + g * 8 + pair * 2 + 1] = hb;
            }
        }
        if (s < 511) {
            __syncthreads();              // drains write-through h stores (vmcnt 0)
            bar_arrive(ctr, g);
            // overlap: x-part of step s+1 (x read-only, cached — L2 now stays warm)
            if (up) {
                f32x16 ax = Z16;
                const __bf16* xr = xb + (size_t)mrow * 65536 + (size_t)(s + 1) * 128;
#pragma unroll
                for (int kt = 0; kt < 8; ++kt)
                    ax = MFMA32(*(const bf16x8*)(xr + kt * 16 + koff), xrg[kt], ax);
                accx = ax;
            }
            bar_wait(ctr, (unsigned)(s + 1) * NWG_E);
        }
    }
}

// ---------------- decoder ----------------
// g < 128  : gate WG (32 gate cols; 8 K-split GEMM waves; all waves gate math)
// g >= 128 : out WG  (one 32x32 out tile; wave 0 GEMM + stores, overlapped with barrier)
__global__ __launch_bounds__(512, 2) void k_dec(
    const __bf16* __restrict__ Wd, const float* __restrict__ bd,
    const __bf16* __restrict__ Wob, const float* __restrict__ bout,
    __bf16* __restrict__ h0, __bf16* __restrict__ h1,
    const float* __restrict__ h32, float* __restrict__ out,
    unsigned* __restrict__ ctr) {
    __shared__ __align__(16) __bf16 sW[32][1032];
    __shared__ float sB[32];
    __shared__ __align__(16) float sGa[128][36];
    __shared__ __align__(16) float sGb[128][36];
    const int g = blockIdx.x, tid = threadIdx.x;
    const int lane = tid & 63, wave = tid >> 6;
    const bool gwg = (g < 128);
    const int go = g - 128;

    if (gwg) {
        for (int i = tid; i < 32 * 128; i += 512) {
            int c = i >> 7, k8 = i & 127;
            *(i32x4*)&sW[c][k8 * 8] = *(const i32x4*)(Wd + ((size_t)g * 32 + c) * 1024 + k8 * 8);
        }
        if (tid < 32) sB[tid] = bd[g * 32 + tid];
    } else {
        for (int i = tid; i < 32 * 128; i += 512) {
            int c = i >> 7, k8 = i & 127;
            *(i32x4*)&sW[c][k8 * 8] =
                *(const i32x4*)(Wob + ((size_t)((go >> 2) * 32 + c)) * 1024 + k8 * 8);
        }
    }
    __syncthreads();

    const int bcol = lane & 31;
    const int koff = (lane >> 5) * 8;
    const int kb = (wave >> 2) * 32;
    const bool up = (wave >= 4);
    const int arow = gwg ? ((wave & 3) * 32 + bcol)   // batch row, gate gemm
                         : ((go & 3) * 32 + bcol);    // batch row, out gemm

    const int erow = tid >> 2, pair = tid & 3;
    const int hidx2 = erow * 512 + g * 4 + pair;
    float ha = 0.f, hb = 0.f;
    if (gwg) {
        ha = h32[erow * 1024 + g * 8 + pair * 2];
        hb = h32[erow * 1024 + g * 8 + pair * 2 + 1];
    }
    float obias = 0.f; int fcol = 0;
    if (!gwg) { fcol = (go >> 2) * 32 + bcol; obias = bout[fcol]; }

    if (gwg) {
        for (int s = 0; s < 512; ++s) {
            const __bf16* hcur = (s & 1) ? h1 : h0;
            __bf16* hnxt = (s & 1) ? h0 : h1;
            {
                f32x16 aA = Z16, aB = Z16;
                const __bf16* hr = hcur + (size_t)arow * 1024 + kb * 16;
                bf16x8 af[16];
#pragma unroll
                for (int i = 0; i < 16; ++i) af[i] = ld_h(hr + i * 16 + koff);
#pragma unroll
                for (int i = 0; i < 16; ++i) {
                    bf16x8 a = af[i];
                    af[i] = ld_h(hr + (16 + i) * 16 + koff);
                    const bf16x8 b = *(const bf16x8*)(&sW[bcol][(kb + i) * 16 + koff]);
                    if (i & 1) aB = MFMA32(a, b, aB); else aA = MFMA32(a, b, aA);
                }
#pragma unroll
                for (int i = 0; i < 16; ++i) {
                    const bf16x8 b = *(const bf16x8*)(&sW[bcol][(kb + 16 + i) * 16 + koff]);
                    if (i & 1) aB = MFMA32(af[i], b, aB); else aA = MFMA32(af[i], b, aA);
                }
                f32x16 acc = aA + aB;
                int rb = (wave & 3) * 32 + 4 * (lane >> 5);
                float (*sg)[36] = up ? sGb : sGa;
#pragma unroll
                for (int r = 0; r < 16; ++r)
                    sg[rb + (r & 3) + 8 * (r >> 2)][bcol] = acc[r];
            }
            __syncthreads();
            {
                f32x4 g0 = *(const f32x4*)&sGa[erow][pair * 8] + *(const f32x4*)&sGb[erow][pair * 8];
                f32x4 g1 = *(const f32x4*)&sGa[erow][pair * 8 + 4] + *(const f32x4*)&sGb[erow][pair * 8 + 4];
                int c0 = pair * 8;
                float r = 1.f / (1.f + __expf(-(g0[0] + sB[c0 + 0])));
                float z = 1.f / (1.f + __expf(-(g0[1] + sB[c0 + 1])));
                float n = tanhf(g0[2] + sB[c0 + 2] + r * (g0[3] + sB[c0 + 3]));
                ha = (1.f - z) * n + z * ha;
                r = 1.f / (1.f + __expf(-(g1[0] + sB[c0 + 4])));
                z = 1.f / (1.f + __expf(-(g1[1] + sB[c0 + 5])));
                n = tanhf(g1[2] + sB[c0 + 6] + r * (g1[3] + sB[c0 + 7]));
                hb = (1.f - z) * n + z * hb;
                pk2 p; p.h[0] = (__bf16)ha; p.h[1] = (__bf16)hb;
                __hip_atomic_store((unsigned*)hnxt + hidx2, p.u, __ATOMIC_RELAXED, __HIP_MEMORY_SCOPE_AGENT);
            }
            __syncthreads();              // drains write-through h stores
            bar_arrive(ctr, g);
            if (s < 511) bar_wait(ctr, (unsigned)(s + 1) * NWG_D);
        }
    } else {
        // out WG: iteration s computes out col 512-s = h_s @ W_out^T + b (s = 1..512)
        for (int s = 0; s <= 512; ++s) {
            const __bf16* hcur = (s & 1) ? h1 : h0;
            const bool cmp = (wave == 0) && (s >= 1);
            f32x16 acc = Z16;
            if (cmp) {
                f32x16 aA = Z16, aB = Z16;
                const __bf16* hr = hcur + (size_t)arow * 1024;
                bf16x8 af[16];
#pragma unroll
                for (int i = 0; i < 16; ++i) af[i] = ld_h(hr + i * 16 + koff);
#pragma unroll
                for (int kt = 0; kt < 48; ++kt) {
                    bf16x8 a = af[kt & 15];
                    af[kt & 15] = ld_h(hr + (kt + 16) * 16 + koff);
                    const bf16x8 b = *(const bf16x8*)(&sW[bcol][kt * 16 + koff]);
                    if (kt & 1) aB = MFMA32(a, b, aB); else aA = MFMA32(a, b, aA);
                }
#pragma unroll
                for (int kt = 48; kt < 64; ++kt) {
                    const bf16x8 b = *(const bf16x8*)(&sW[bcol][kt * 16 + koff]);
                    if (kt & 1) aB = MFMA32(af[kt & 15], b, aB); else aA = MFMA32(af[kt & 15], b, aA);
                }
                acc = aA + aB;
            }
            if (s < 512) bar_arrive(ctr, g);   // h reads already consumed into acc
            if (cmp) {
                // write-through stores, overlapped with the barrier window
                int rb = 4 * (lane >> 5);
#pragma unroll
                for (int r = 0; r < 16; ++r) {
                    int b = (go & 3) * 32 + rb + (r & 3) + 8 * (r >> 2);
                    fu cv; cv.f = acc[r] + obias;
                    __hip_atomic_store((unsigned*)(out + ((size_t)b * 512 + (size_t)(512 - s)) * 128 + fcol),
                                       cv.u, __ATOMIC_RELAXED, __HIP_MEMORY_SCOPE_AGENT);
                }
            }
            if (s < 512) bar_wait(ctr, (unsigned)(s + 1) * NWG_D);
        }
    }
}

// ---------------- launch ----------------
extern "C" void kernel_launch(void* const* d_in, const int* in_sizes, int n_in,
                              void* d_out, int out_size, void* d_ws, size_t ws_size,
                              hipStream_t stream) {
    (void)in_sizes; (void)n_in; (void)out_size; (void)ws_size;
    const float* x    = (const float*)d_in[0];
    const float* Wihe = (const float*)d_in[1];
    const float* Whhe = (const float*)d_in[2];
    const float* bihe = (const float*)d_in[3];
    const float* bhhe = (const float*)d_in[4];
    const float* Wihd = (const float*)d_in[5];
    const float* Whhd = (const float*)d_in[6];
    const float* bihd = (const float*)d_in[7];
    const float* bhhd = (const float*)d_in[8];
    const float* Wout = (const float*)d_in[9];
    const float* bout = (const float*)d_in[10];

    char* ws = (char*)d_ws;
    __bf16*   h0  = (__bf16*)(ws + O_H0);
    __bf16*   h1  = (__bf16*)(ws + O_H1);
    float*    h32 = (float*)(ws + O_H32);
    unsigned* ctr = (unsigned*)(ws + O_CTR);
    __bf16*   xbf = (__bf16*)(ws + O_XB);
    __bf16*   Weh = (__bf16*)(ws + O_WEH);
    __bf16*   Wex = (__bf16*)(ws + O_WEX);
    float*    be  = (float*)(ws + O_BE);
    __bf16*   Wd  = (__bf16*)(ws + O_WD);
    float*    bd  = (float*)(ws + O_BD);
    __bf16*   Wc  = (__bf16*)(ws + O_WC);
    __bf16*   Wob = (__bf16*)(ws + O_WOB);

    hipMemsetAsync(ws, 0, O_ZERO_END, stream);   // h0/h1/h32 + both sync blocks

    k_xcvt<<<4096, 256, 0, stream>>>(x, xbf, B_ * S_ * F_);
    k_pack_enc<<<NWG_E, 256, 0, stream>>>(Wihe, Whhe, bihe, bhhe, Weh, Wex, be);
    k_wcomb<<<384, 256, 0, stream>>>(Wihd, Wout, Wc);
    k_pack_dec<<<NWG_E, 256, 0, stream>>>(Whhd, Wc, Wihd, bihd, bhhd, bout, Wd, bd);
    k_woutb<<<512, 256, 0, stream>>>(Wout, Wob, F_ * L_);

    k_enc<<<NWG_E, 512, 0, stream>>>(xbf, Weh, Wex, be, h0, h1, h32, ctr);
    k_dec<<<NWG_D, 512, 0, stream>>>(Wd, bd, Wob, bout, h0, h1, h32, (float*)d_out,
                                     ctr + 1024);
}

// Round 5
// 11243.383 us; speedup vs baseline: 1.5793x; 1.5793x over previous
//
#include <hip/hip_runtime.h>
#include <hip/hip_bf16.h>

// RecurrentAE on MI355X — round 9.
//  - r8 post-mortem: "h from LLC" failed due to ATOMIC-load codegen (2x insts, unpipelined,
//    naked 900cy latency), not due to the no-inv architecture. r9 keeps the architecture:
//    NO invalidates, NO leader/epoch, single-hop all-poll barrier.
//  - h loads: plain inline-asm global_load_dwordx4 sc0 sc1 (uncached, reads coherence point),
//    issued in 16-deep volatile batches; s_waitcnt vmcnt(0) REGISTER-TIED to the loaded
//    frags + sched_barrier(0) before MFMAs (rule-18 discipline).
//  - h stores: write-through agent atomics, drained by __syncthreads before arrive (as r7).
//  - x/weights: plain cached loads — nothing ever invalidates, L2 stays warm (enc FETCH
//    599MB should collapse).
//  - out-WGs: 4-wave K-split (k-quarter partials -> LDS reduce) — removes the single-wave
//    64-frag straggler from the quorum.

#define B_ 128
#define S_ 512
#define F_ 128
#define L_ 1024
#define U_ 8
#define NWG_E 128
#define NWG_D 144          // 128 gate WGs + 16 out WGs

typedef __bf16 bf16x8 __attribute__((ext_vector_type(8)));
typedef float  f32x4  __attribute__((ext_vector_type(4)));
typedef float  f32x16 __attribute__((ext_vector_type(16)));
typedef int    i32x4  __attribute__((ext_vector_type(4)));
typedef unsigned long long u64;

union pk2 { unsigned u; __bf16 h[2]; };
union fu  { float f; unsigned u; };

#define MFMA32(a, b, c) __builtin_amdgcn_mfma_f32_32x32x16_bf16(a, b, c, 0, 0, 0)
#define Z16 f32x16{0.f,0.f,0.f,0.f,0.f,0.f,0.f,0.f,0.f,0.f,0.f,0.f,0.f,0.f,0.f,0.f}

// uncached (LLC-direct) 16B load — plain vector load, fully pipelined
#define LDG16(dst, p) asm volatile("global_load_dwordx4 %0, %1, off sc0 sc1" : "=v"(dst) : "v"(p))
// wait-all, register-tied to a 16-frag batch so consumers can't be scheduled above it
#define VMWAIT16(a) asm volatile("s_waitcnt vmcnt(0)" \
    : "+v"(a[0]),"+v"(a[1]),"+v"(a[2]),"+v"(a[3]),"+v"(a[4]),"+v"(a[5]),"+v"(a[6]),"+v"(a[7]), \
      "+v"(a[8]),"+v"(a[9]),"+v"(a[10]),"+v"(a[11]),"+v"(a[12]),"+v"(a[13]),"+v"(a[14]),"+v"(a[15]) \
    :: "memory")
#define SB0() __builtin_amdgcn_sched_barrier(0)

// ---------------- workspace layout (bytes) ----------------
#define O_H0   0                          // bf16 [128][1024]
#define O_H1   (256*1024)                 // bf16 [128][1024]
#define O_H32  (512*1024)                 // f32  [128][1024]
#define O_CTR  (1024*1024)                // sync: enc @ +0, dec @ +4096 (1024 u32 each)
#define O_ZERO_END (1024*1024 + 8192)
#define O_XB   O_ZERO_END                 // bf16 [128][512][128] = 16777216
#define O_WEH  (O_XB  + 16777216)         // bf16 [128][32][1024] = 8388608
#define O_WEX  (O_WEH + 8388608)          // bf16 [128][32][128]  = 1048576
#define O_BE   (O_WEX + 1048576)          // f32  [128][32]       = 16384
#define O_WD   (O_BE  + 16384)            // bf16 [128][32][1024] = 8388608
#define O_BD   (O_WD  + 8388608)          // f32  [128][32]       = 16384
#define O_WC   (O_BD  + 16384)            // bf16 [3072][1024]    = 6291456
#define O_WOB  (O_WC  + 6291456)          // bf16 [128][1024]     = 262144
// total ~42 MB

// ---------------- prep kernels ----------------

__global__ void k_xcvt(const float* __restrict__ x, __bf16* __restrict__ xb, int n) {
    int i = blockIdx.x * 256 + threadIdx.x;
    int stride = gridDim.x * 256;
    for (; i < n; i += stride) xb[i] = (__bf16)x[i];
}

__global__ void k_woutb(const float* __restrict__ Wout, __bf16* __restrict__ Wob, int n) {
    int i = blockIdx.x * 256 + threadIdx.x;
    if (i < n) Wob[i] = (__bf16)Wout[i];
}

// encoder pack: 32 cols/WG, 4 per unit {r, z, n_i, n_h}
__global__ void k_pack_enc(const float* __restrict__ Wih, const float* __restrict__ Whh,
                           const float* __restrict__ bih, const float* __restrict__ bhh,
                           __bf16* __restrict__ Weh, __bf16* __restrict__ Wex,
                           float* __restrict__ be) {
    int g = blockIdx.x, tid = threadIdx.x;
    for (int i = tid; i < 32 * 1024; i += 256) {
        int c = i >> 10, k = i & 1023;
        int u = g * U_ + (c >> 2), gate = c & 3;
        float v = 0.f;
        if (gate == 0)      v = Whh[(size_t)u * 1024 + k];
        else if (gate == 1) v = Whh[(size_t)(1024 + u) * 1024 + k];
        else if (gate == 3) v = Whh[(size_t)(2048 + u) * 1024 + k];
        Weh[((size_t)g * 32 + c) * 1024 + k] = (__bf16)v;
    }
    for (int i = tid; i < 32 * 128; i += 256) {
        int c = i >> 7, k = i & 127;
        int u = g * U_ + (c >> 2), gate = c & 3;
        float v = 0.f;
        if (gate == 0)      v = Wih[(size_t)u * 128 + k];
        else if (gate == 1) v = Wih[(size_t)(1024 + u) * 128 + k];
        else if (gate == 2) v = Wih[(size_t)(2048 + u) * 128 + k];
        Wex[((size_t)g * 32 + c) * 128 + k] = (__bf16)v;
    }
    if (tid < 32) {
        int c = tid, u = g * U_ + (c >> 2), gate = c & 3;
        float v;
        if (gate == 0)      v = bih[u] + bhh[u];
        else if (gate == 1) v = bih[1024 + u] + bhh[1024 + u];
        else if (gate == 2) v = bih[2048 + u];
        else                v = bhh[2048 + u];
        be[g * 32 + c] = v;
    }
}

// W_comb = W_ih_d @ W_out
__global__ void k_wcomb(const float* __restrict__ Wihd, const float* __restrict__ Wout,
                        __bf16* __restrict__ Wc) {
    __shared__ float a[8][128];
    int r0 = blockIdx.x * 8, tid = threadIdx.x;
    for (int i = tid; i < 8 * 128; i += 256)
        a[i >> 7][i & 127] = Wihd[(size_t)(r0 + (i >> 7)) * 128 + (i & 127)];
    __syncthreads();
    for (int j = tid; j < 1024; j += 256) {
        float acc[8] = {0, 0, 0, 0, 0, 0, 0, 0};
        for (int f = 0; f < 128; ++f) {
            float w = Wout[(size_t)f * 1024 + j];
#pragma unroll
            for (int r = 0; r < 8; ++r) acc[r] += a[r][f] * w;
        }
        for (int r = 0; r < 8; ++r) Wc[(size_t)(r0 + r) * 1024 + j] = (__bf16)acc[r];
    }
}

// decoder pack: 32 cols/WG {r:Whh+Wc, z:Whh+Wc, n_i:Wc, n_h:Whh}
__global__ void k_pack_dec(const float* __restrict__ Whhd, const __bf16* __restrict__ Wc,
                           const float* __restrict__ Wihd,
                           const float* __restrict__ bihd, const float* __restrict__ bhhd,
                           const float* __restrict__ bout,
                           __bf16* __restrict__ Wd, float* __restrict__ bd) {
    int g = blockIdx.x, tid = threadIdx.x;
    for (int i = tid; i < 32 * 1024; i += 256) {
        int c = i >> 10, k = i & 1023;
        int u = g * U_ + (c >> 2), gate = c & 3;
        float v;
        if (gate == 0)      v = Whhd[(size_t)u * 1024 + k] + (float)Wc[(size_t)u * 1024 + k];
        else if (gate == 1) v = Whhd[(size_t)(1024 + u) * 1024 + k] + (float)Wc[(size_t)(1024 + u) * 1024 + k];
        else if (gate == 2) v = (float)Wc[(size_t)(2048 + u) * 1024 + k];
        else                v = Whhd[(size_t)(2048 + u) * 1024 + k];
        Wd[((size_t)g * 32 + c) * 1024 + k] = (__bf16)v;
    }
    if (tid < 32) {
        int c = tid;
        int u = g * U_ + (c >> 2), gate = c & 3;
        int row = (gate == 0) ? u : (gate == 1) ? (1024 + u) : (2048 + u);
        float v;
        if (gate <= 1) {
            float d = 0.f;
            for (int f = 0; f < 128; ++f) d += Wihd[(size_t)row * 128 + f] * bout[f];
            v = d + bihd[row] + bhhd[row];
        } else if (gate == 2) {
            float d = 0.f;
            for (int f = 0; f < 128; ++f) d += Wihd[(size_t)row * 128 + f] * bout[f];
            v = d + bihd[row];
        } else {
            v = bhhd[row];
        }
        bd[g * 32 + c] = v;
    }
}

// ---------------- barrier: 16 counters (128B apart), single-hop all-poll, NO inv ----------

__device__ __forceinline__ void bar_arrive(unsigned* base, int g) {
    if (threadIdx.x == 0)
        __hip_atomic_fetch_add(base + (g & 15) * 32, 1u,
                               __ATOMIC_RELAXED, __HIP_MEMORY_SCOPE_AGENT);
}

__device__ __forceinline__ void bar_wait(unsigned* base, unsigned tgt) {
    if (threadIdx.x == 0) {
        for (;;) {
            unsigned sum = 0;
#pragma unroll
            for (int j = 0; j < 16; ++j)
                sum += __hip_atomic_load(base + j * 32, __ATOMIC_RELAXED, __HIP_MEMORY_SCOPE_AGENT);
            if (sum >= tgt) break;
            __builtin_amdgcn_s_sleep(1);
        }
    }
    __syncthreads();
}

// ---------------- encoder ----------------
// 8 GEMM waves: wave w (w<4) rows (w&3)*32, K-frags 0..31 -> sGa;
//               wave w+4     same rows,     K-frags 32..63 -> sGb (+ x part, overlapped).
__global__ __launch_bounds__(512, 2) void k_enc(
    const __bf16* __restrict__ xb, const __bf16* __restrict__ Weh,
    const __bf16* __restrict__ Wex, const float* __restrict__ be,
    __bf16* __restrict__ h0, __bf16* __restrict__ h1,
    float* __restrict__ h32, unsigned* __restrict__ ctr) {
    __shared__ __align__(16) __bf16 sWh[32][1032];
    __shared__ __align__(16) __bf16 sWx[32][136];
    __shared__ float sB[32];
    __shared__ __align__(16) float sGa[128][36];
    __shared__ __align__(16) float sGb[128][36];
    const int g = blockIdx.x, tid = threadIdx.x;
    const int lane = tid & 63, wave = tid >> 6;

    for (int i = tid; i < 32 * 128; i += 512) {
        int c = i >> 7, k8 = i & 127;
        *(i32x4*)&sWh[c][k8 * 8] = *(const i32x4*)(Weh + ((size_t)g * 32 + c) * 1024 + k8 * 8);
    }
    for (int i = tid; i < 32 * 16; i += 512) {
        int c = i >> 4, k8 = i & 15;
        *(i32x4*)&sWx[c][k8 * 8] = *(const i32x4*)(Wex + ((size_t)g * 32 + c) * 128 + k8 * 8);
    }
    if (tid < 32) sB[tid] = be[g * 32 + tid];
    __syncthreads();

    const int bcol = lane & 31;
    const int koff = (lane >> 5) * 8;
    const int mrow = (wave & 3) * 32 + bcol;
    const int kb = (wave >> 2) * 32;           // this wave's K-frag base
    const bool up = (wave >= 4);

    bf16x8 xrg[8];
    if (up) {
#pragma unroll
        for (int kt = 0; kt < 8; ++kt) xrg[kt] = *(const bf16x8*)(&sWx[bcol][kt * 16 + koff]);
    }

    const int erow = tid >> 2, pair = tid & 3;
    const int hidx2 = erow * 512 + g * 4 + pair;
    float ha = 0.f, hb = 0.f;

    // x-part of step 0 (upper waves)
    f32x16 accx = Z16;
    if (up) {
        const __bf16* xr = xb + (size_t)mrow * 65536;
#pragma unroll
        for (int kt = 0; kt < 8; ++kt)
            accx = MFMA32(*(const bf16x8*)(xr + kt * 16 + koff), xrg[kt], accx);
    }

    for (int s = 0; s < 512; ++s) {
        const __bf16* hcur = (s & 1) ? h1 : h0;
        __bf16* hnxt = (s & 1) ? h0 : h1;
        {
            f32x16 aA = up ? accx : Z16;
            f32x16 aB = Z16;
            const __bf16* hr = hcur + (size_t)mrow * 1024 + kb * 16;
            bf16x8 af[16];
#pragma unroll
            for (int i = 0; i < 16; ++i) LDG16(af[i], hr + i * 16 + koff);
            VMWAIT16(af); SB0();
#pragma unroll
            for (int i = 0; i < 16; ++i) {
                const bf16x8 b = *(const bf16x8*)(&sWh[bcol][(kb + i) * 16 + koff]);
                if (i & 1) aB = MFMA32(af[i], b, aB); else aA = MFMA32(af[i], b, aA);
                LDG16(af[i], hr + (16 + i) * 16 + koff);
            }
            VMWAIT16(af); SB0();
#pragma unroll
            for (int i = 0; i < 16; ++i) {
                const bf16x8 b = *(const bf16x8*)(&sWh[bcol][(kb + 16 + i) * 16 + koff]);
                if (i & 1) aB = MFMA32(af[i], b, aB); else aA = MFMA32(af[i], b, aA);
            }
            f32x16 acc = aA + aB;
            // C frag: col = lane&31, row = (r&3) + 8*(r>>2) + 4*(lane>>5)
            int rb = (wave & 3) * 32 + 4 * (lane >> 5);
            float (*sg)[36] = up ? sGb : sGa;
#pragma unroll
            for (int r = 0; r < 16; ++r)
                sg[rb + (r & 3) + 8 * (r >> 2)][bcol] = acc[r];
        }
        __syncthreads();
        {
            f32x4 g0 = *(const f32x4*)&sGa[erow][pair * 8] + *(const f32x4*)&sGb[erow][pair * 8];
            f32x4 g1 = *(const f32x4*)&sGa[erow][pair * 8 + 4] + *(const f32x4*)&sGb[erow][pair * 8 + 4];
            int c0 = pair * 8;
            float r = 1.f / (1.f + __expf(-(g0[0] + sB[c0 + 0])));
            float z = 1.f / (1.f + __expf(-(g0[1] + sB[c0 + 1])));
            float n = tanhf(g0[2] + sB[c0 + 2] + r * (g0[3] + sB[c0 + 3]));
            ha = (1.f - z) * n + z * ha;
            r = 1.f / (1.f + __expf(-(g1[0] + sB[c0 + 4])));
            z = 1.f / (1.f + __expf(-(g1[1] + sB[c0 + 5])));
            n = tanhf(g1[2] + sB[c0 + 6] + r * (g1[3] + sB[c0 + 7]));
            hb = (1.f - z) * n + z * hb;
            pk2 p; p.h[0] = (__bf16)ha; p.h[1] = (__bf16)hb;
            __hip_atomic_store((unsigned*)hnxt + hidx2, p.u, __ATOMIC_RELAXED, __HIP_MEMORY_SCOPE_AGENT);
            if (s == 511) {
                h32[erow * 1024 + g * 8 + pair * 2]     = ha;
                h32[erow * 1024 + g * 8 + pair * 2 + 1] = hb;
            }
        }
        if (s < 511) {
            __syncthreads();              // drains write-through h stores (vmcnt 0)
            bar_arrive(ctr, g);
            // overlap: x-part of step s+1 (x read-only, cached — L2 stays warm, no inv ever)
            if (up) {
                f32x16 ax = Z16;
                const __bf16* xr = xb + (size_t)mrow * 65536 + (size_t)(s + 1) * 128;
#pragma unroll
                for (int kt = 0; kt < 8; ++kt)
                    ax = MFMA32(*(const bf16x8*)(xr + kt * 16 + koff), xrg[kt], ax);
                accx = ax;
            }
            bar_wait(ctr, (unsigned)(s + 1) * NWG_E);
        }
    }
}

// ---------------- decoder ----------------
// g < 128  : gate WG (32 gate cols; 8 K-split GEMM waves; all waves gate math)
// g >= 128 : out WG  (one 32x32 out tile; 4-wave K-split partials -> LDS reduce -> store)
__global__ __launch_bounds__(512, 2) void k_dec(
    const __bf16* __restrict__ Wd, const float* __restrict__ bd,
    const __bf16* __restrict__ Wob, const float* __restrict__ bout,
    __bf16* __restrict__ h0, __bf16* __restrict__ h1,
    const float* __restrict__ h32, float* __restrict__ out,
    unsigned* __restrict__ ctr) {
    __shared__ __align__(16) __bf16 sW[32][1032];
    __shared__ float sB[32];
    __shared__ __align__(16) float sGa[128][36];
    __shared__ __align__(16) float sGb[128][36];
    const int g = blockIdx.x, tid = threadIdx.x;
    const int lane = tid & 63, wave = tid >> 6;
    const bool gwg = (g < 128);
    const int go = g - 128;

    if (gwg) {
        for (int i = tid; i < 32 * 128; i += 512) {
            int c = i >> 7, k8 = i & 127;
            *(i32x4*)&sW[c][k8 * 8] = *(const i32x4*)(Wd + ((size_t)g * 32 + c) * 1024 + k8 * 8);
        }
        if (tid < 32) sB[tid] = bd[g * 32 + tid];
    } else {
        for (int i = tid; i < 32 * 128; i += 512) {
            int c = i >> 7, k8 = i & 127;
            *(i32x4*)&sW[c][k8 * 8] =
                *(const i32x4*)(Wob + ((size_t)((go >> 2) * 32 + c)) * 1024 + k8 * 8);
        }
        if (tid < 32) sB[tid] = bout[(go >> 2) * 32 + tid];
    }
    __syncthreads();

    const int bcol = lane & 31;
    const int koff = (lane >> 5) * 8;
    const int kb = (wave >> 2) * 32;
    const bool up = (wave >= 4);
    const int arow = gwg ? ((wave & 3) * 32 + bcol)   // batch row, gate gemm
                         : ((go & 3) * 32 + bcol);    // batch row, out gemm

    const int erow = tid >> 2, pair = tid & 3;
    const int hidx2 = erow * 512 + g * 4 + pair;
    float ha = 0.f, hb = 0.f;
    if (gwg) {
        ha = h32[erow * 1024 + g * 8 + pair * 2];
        hb = h32[erow * 1024 + g * 8 + pair * 2 + 1];
    }

    if (gwg) {
        for (int s = 0; s < 512; ++s) {
            const __bf16* hcur = (s & 1) ? h1 : h0;
            __bf16* hnxt = (s & 1) ? h0 : h1;
            {
                f32x16 aA = Z16, aB = Z16;
                const __bf16* hr = hcur + (size_t)arow * 1024 + kb * 16;
                bf16x8 af[16];
#pragma unroll
                for (int i = 0; i < 16; ++i) LDG16(af[i], hr + i * 16 + koff);
                VMWAIT16(af); SB0();
#pragma unroll
                for (int i = 0; i < 16; ++i) {
                    const bf16x8 b = *(const bf16x8*)(&sW[bcol][(kb + i) * 16 + koff]);
                    if (i & 1) aB = MFMA32(af[i], b, aB); else aA = MFMA32(af[i], b, aA);
                    LDG16(af[i], hr + (16 + i) * 16 + koff);
                }
                VMWAIT16(af); SB0();
#pragma unroll
                for (int i = 0; i < 16; ++i) {
                    const bf16x8 b = *(const bf16x8*)(&sW[bcol][(kb + 16 + i) * 16 + koff]);
                    if (i & 1) aB = MFMA32(af[i], b, aB); else aA = MFMA32(af[i], b, aA);
                }
                f32x16 acc = aA + aB;
                int rb = (wave & 3) * 32 + 4 * (lane >> 5);
                float (*sg)[36] = up ? sGb : sGa;
#pragma unroll
                for (int r = 0; r < 16; ++r)
                    sg[rb + (r & 3) + 8 * (r >> 2)][bcol] = acc[r];
            }
            __syncthreads();
            {
                f32x4 g0 = *(const f32x4*)&sGa[erow][pair * 8] + *(const f32x4*)&sGb[erow][pair * 8];
                f32x4 g1 = *(const f32x4*)&sGa[erow][pair * 8 + 4] + *(const f32x4*)&sGb[erow][pair * 8 + 4];
                int c0 = pair * 8;
                float r = 1.f / (1.f + __expf(-(g0[0] + sB[c0 + 0])));
                float z = 1.f / (1.f + __expf(-(g0[1] + sB[c0 + 1])));
                float n = tanhf(g0[2] + sB[c0 + 2] + r * (g0[3] + sB[c0 + 3]));
                ha = (1.f - z) * n + z * ha;
                r = 1.f / (1.f + __expf(-(g1[0] + sB[c0 + 4])));
                z = 1.f / (1.f + __expf(-(g1[1] + sB[c0 + 5])));
                n = tanhf(g1[2] + sB[c0 + 6] + r * (g1[3] + sB[c0 + 7]));
                hb = (1.f - z) * n + z * hb;
                pk2 p; p.h[0] = (__bf16)ha; p.h[1] = (__bf16)hb;
                __hip_atomic_store((unsigned*)hnxt + hidx2, p.u, __ATOMIC_RELAXED, __HIP_MEMORY_SCOPE_AGENT);
            }
            __syncthreads();              // drains write-through h stores
            bar_arrive(ctr, g);
            if (s < 511) bar_wait(ctr, (unsigned)(s + 1) * NWG_D);
        }
    } else {
        // out WG: iteration s computes out col 512-s = h_s @ W_out^T + b (s = 1..512).
        // 4 GEMM waves, each a K-quarter (16 frags) of the same 32x32 tile; partials in
        // sGo; all 512 threads reduce + store (overlapped with the barrier poll window).
        __shared__ __align__(16) float sGo[4][32][32];
        for (int s = 0; s <= 512; ++s) {
            const __bf16* hcur = (s & 1) ? h1 : h0;
            const bool cmp = (wave < 4) && (s >= 1);
            if (cmp) {
                f32x16 aA = Z16, aB = Z16;
                const __bf16* hr = hcur + (size_t)arow * 1024 + (wave * 16) * 16;
                bf16x8 af[16];
#pragma unroll
                for (int i = 0; i < 16; ++i) LDG16(af[i], hr + i * 16 + koff);
                VMWAIT16(af); SB0();
#pragma unroll
                for (int i = 0; i < 16; ++i) {
                    const bf16x8 b = *(const bf16x8*)(&sW[bcol][(wave * 16 + i) * 16 + koff]);
                    if (i & 1) aB = MFMA32(af[i], b, aB); else aA = MFMA32(af[i], b, aA);
                }
                f32x16 acc = aA + aB;
                int rb = 4 * (lane >> 5);
#pragma unroll
                for (int r = 0; r < 16; ++r)
                    sGo[wave][rb + (r & 3) + 8 * (r >> 2)][bcol] = acc[r];
            }
            __syncthreads();              // h consumed into regs/partials; sGo visible
            if (s < 512) bar_arrive(ctr, g);
            if (s >= 1) {
                // reduce 4 partials, add bias, store 2 elements per thread
                int c = tid & 31, r0 = (tid >> 5) & 15;
#pragma unroll
                for (int hh = 0; hh < 2; ++hh) {
                    int r = r0 + hh * 16;
                    fu cv;
                    cv.f = sGo[0][r][c] + sGo[1][r][c] + sGo[2][r][c] + sGo[3][r][c] + sB[c];
                    size_t off = ((size_t)((go & 3) * 32 + r) * 512 + (size_t)(512 - s)) * 128
                               + (go >> 2) * 32 + c;
                    __hip_atomic_store((unsigned*)(out + off), cv.u,
                                       __ATOMIC_RELAXED, __HIP_MEMORY_SCOPE_AGENT);
                }
            }
            if (s < 512) bar_wait(ctr, (unsigned)(s + 1) * NWG_D);
        }
    }
}

// ---------------- launch ----------------
extern "C" void kernel_launch(void* const* d_in, const int* in_sizes, int n_in,
                              void* d_out, int out_size, void* d_ws, size_t ws_size,
                              hipStream_t stream) {
    (void)in_sizes; (void)n_in; (void)out_size; (void)ws_size;
    const float* x    = (const float*)d_in[0];
    const float* Wihe = (const float*)d_in[1];
    const float* Whhe = (const float*)d_in[2];
    const float* bihe = (const float*)d_in[3];
    const float* bhhe = (const float*)d_in[4];
    const float* Wihd = (const float*)d_in[5];
    const float* Whhd = (const float*)d_in[6];
    const float* bihd = (const float*)d_in[7];
    const float* bhhd = (const float*)d_in[8];
    const float* Wout = (const float*)d_in[9];
    const float* bout = (const float*)d_in[10];

    char* ws = (char*)d_ws;
    __bf16*   h0  = (__bf16*)(ws + O_H0);
    __bf16*   h1  = (__bf16*)(ws + O_H1);
    float*    h32 = (float*)(ws + O_H32);
    unsigned* ctr = (unsigned*)(ws + O_CTR);
    __bf16*   xbf = (__bf16*)(ws + O_XB);
    __bf16*   Weh = (__bf16*)(ws + O_WEH);
    __bf16*   Wex = (__bf16*)(ws + O_WEX);
    float*    be  = (float*)(ws + O_BE);
    __bf16*   Wd  = (__bf16*)(ws + O_WD);
    float*    bd  = (float*)(ws + O_BD);
    __bf16*   Wc  = (__bf16*)(ws + O_WC);
    __bf16*   Wob = (__bf16*)(ws + O_WOB);

    hipMemsetAsync(ws, 0, O_ZERO_END, stream);   // h0/h1/h32 + both sync blocks

    k_xcvt<<<4096, 256, 0, stream>>>(x, xbf, B_ * S_ * F_);
    k_pack_enc<<<NWG_E, 256, 0, stream>>>(Wihe, Whhe, bihe, bhhe, Weh, Wex, be);
    k_wcomb<<<384, 256, 0, stream>>>(Wihd, Wout, Wc);
    k_pack_dec<<<NWG_E, 256, 0, stream>>>(Whhd, Wc, Wihd, bihd, bhhd, bout, Wd, bd);
    k_woutb<<<512, 256, 0, stream>>>(Wout, Wob, F_ * L_);

    k_enc<<<NWG_E, 512, 0, stream>>>(xbf, Weh, Wex, be, h0, h1, h32, ctr);
    k_dec<<<NWG_D, 512, 0, stream>>>(Wd, bd, Wob, bout, h0, h1, h32, (float*)d_out,
                                     ctr + 1024);
}

// Round 6
// 6005.353 us; speedup vs baseline: 2.9568x; 1.8722x over previous
//
#include <hip/hip_runtime.h>
#include <hip/hip_bf16.h>

// RecurrentAE on MI355X — round 10.
//  - r9 post-mortem: no-inv architecture correct but ~11 µs/step; h access pattern wastes
//    LLC bandwidth on transaction count: row-major h makes every dwordx4 touch 32 distinct
//    128B lines (16B used per line), for loads AND stores, uncached AND cached paths.
//  - NEW: transposed h layout [kgroup=col/8][row][8cols]. Stores: each WG writes one
//    contiguous 2KB plane (256B runs per wave). Loads: MFMA A-frag = 8 consecutive cols at
//    8-aligned boundary = one 16B load; half-wave (32 rows, same kgroup) = 512B contiguous.
//    ~8x fewer LLC transactions on the 36MB/step h broadcast.
//  - Keep r9: NO invalidates, single-hop all-poll barrier (16 counters), inline-asm
//    global_load_dwordx4 sc0 sc1 h loads (16-deep, register-tied vmcnt + sched_barrier),
//    write-through h stores, 4-wave K-split out-WGs, weights/x plain cached (L2 warm).

#define B_ 128
#define S_ 512
#define F_ 128
#define L_ 1024
#define U_ 8
#define NWG_E 128
#define NWG_D 144          // 128 gate WGs + 16 out WGs

typedef __bf16 bf16x8 __attribute__((ext_vector_type(8)));
typedef float  f32x4  __attribute__((ext_vector_type(4)));
typedef float  f32x16 __attribute__((ext_vector_type(16)));
typedef int    i32x4  __attribute__((ext_vector_type(4)));
typedef unsigned long long u64;

union pk2 { unsigned u; __bf16 h[2]; };
union fu  { float f; unsigned u; };

#define MFMA32(a, b, c) __builtin_amdgcn_mfma_f32_32x32x16_bf16(a, b, c, 0, 0, 0)
#define Z16 f32x16{0.f,0.f,0.f,0.f,0.f,0.f,0.f,0.f,0.f,0.f,0.f,0.f,0.f,0.f,0.f,0.f}

// uncached (LLC-direct) 16B load — plain vector load, fully pipelined
#define LDG16(dst, p) asm volatile("global_load_dwordx4 %0, %1, off sc0 sc1" : "=v"(dst) : "v"(p))
// wait-all, register-tied to a 16-frag batch so consumers can't be scheduled above it
#define VMWAIT16(a) asm volatile("s_waitcnt vmcnt(0)" \
    : "+v"(a[0]),"+v"(a[1]),"+v"(a[2]),"+v"(a[3]),"+v"(a[4]),"+v"(a[5]),"+v"(a[6]),"+v"(a[7]), \
      "+v"(a[8]),"+v"(a[9]),"+v"(a[10]),"+v"(a[11]),"+v"(a[12]),"+v"(a[13]),"+v"(a[14]),"+v"(a[15]) \
    :: "memory")
#define SB0() __builtin_amdgcn_sched_barrier(0)

// ---------------- workspace layout (bytes) ----------------
#define O_H0   0                          // bf16 [128 kgrp][128 row][8 col]
#define O_H1   (256*1024)                 // bf16 same
#define O_H32  (512*1024)                 // f32  [128][1024] (row-major, small)
#define O_CTR  (1024*1024)                // sync: enc @ +0, dec @ +4096 (1024 u32 each)
#define O_ZERO_END (1024*1024 + 8192)
#define O_XB   O_ZERO_END                 // bf16 [128][512][128] = 16777216
#define O_WEH  (O_XB  + 16777216)         // bf16 [128][32][1024] = 8388608
#define O_WEX  (O_WEH + 8388608)          // bf16 [128][32][128]  = 1048576
#define O_BE   (O_WEX + 1048576)          // f32  [128][32]       = 16384
#define O_WD   (O_BE  + 16384)            // bf16 [128][32][1024] = 8388608
#define O_BD   (O_WD  + 8388608)          // f32  [128][32]       = 16384
#define O_WC   (O_BD  + 16384)            // bf16 [3072][1024]    = 6291456
#define O_WOB  (O_WC  + 6291456)          // bf16 [128][1024]     = 262144
// total ~42 MB

// ---------------- prep kernels ----------------

__global__ void k_xcvt(const float* __restrict__ x, __bf16* __restrict__ xb, int n) {
    int i = blockIdx.x * 256 + threadIdx.x;
    int stride = gridDim.x * 256;
    for (; i < n; i += stride) xb[i] = (__bf16)x[i];
}

__global__ void k_woutb(const float* __restrict__ Wout, __bf16* __restrict__ Wob, int n) {
    int i = blockIdx.x * 256 + threadIdx.x;
    if (i < n) Wob[i] = (__bf16)Wout[i];
}

// encoder pack: 32 cols/WG, 4 per unit {r, z, n_i, n_h}
__global__ void k_pack_enc(const float* __restrict__ Wih, const float* __restrict__ Whh,
                           const float* __restrict__ bih, const float* __restrict__ bhh,
                           __bf16* __restrict__ Weh, __bf16* __restrict__ Wex,
                           float* __restrict__ be) {
    int g = blockIdx.x, tid = threadIdx.x;
    for (int i = tid; i < 32 * 1024; i += 256) {
        int c = i >> 10, k = i & 1023;
        int u = g * U_ + (c >> 2), gate = c & 3;
        float v = 0.f;
        if (gate == 0)      v = Whh[(size_t)u * 1024 + k];
        else if (gate == 1) v = Whh[(size_t)(1024 + u) * 1024 + k];
        else if (gate == 3) v = Whh[(size_t)(2048 + u) * 1024 + k];
        Weh[((size_t)g * 32 + c) * 1024 + k] = (__bf16)v;
    }
    for (int i = tid; i < 32 * 128; i += 256) {
        int c = i >> 7, k = i & 127;
        int u = g * U_ + (c >> 2), gate = c & 3;
        float v = 0.f;
        if (gate == 0)      v = Wih[(size_t)u * 128 + k];
        else if (gate == 1) v = Wih[(size_t)(1024 + u) * 128 + k];
        else if (gate == 2) v = Wih[(size_t)(2048 + u) * 128 + k];
        Wex[((size_t)g * 32 + c) * 128 + k] = (__bf16)v;
    }
    if (tid < 32) {
        int c = tid, u = g * U_ + (c >> 2), gate = c & 3;
        float v;
        if (gate == 0)      v = bih[u] + bhh[u];
        else if (gate == 1) v = bih[1024 + u] + bhh[1024 + u];
        else if (gate == 2) v = bih[2048 + u];
        else                v = bhh[2048 + u];
        be[g * 32 + c] = v;
    }
}

// W_comb = W_ih_d @ W_out
__global__ void k_wcomb(const float* __restrict__ Wihd, const float* __restrict__ Wout,
                        __bf16* __restrict__ Wc) {
    __shared__ float a[8][128];
    int r0 = blockIdx.x * 8, tid = threadIdx.x;
    for (int i = tid; i < 8 * 128; i += 256)
        a[i >> 7][i & 127] = Wihd[(size_t)(r0 + (i >> 7)) * 128 + (i & 127)];
    __syncthreads();
    for (int j = tid; j < 1024; j += 256) {
        float acc[8] = {0, 0, 0, 0, 0, 0, 0, 0};
        for (int f = 0; f < 128; ++f) {
            float w = Wout[(size_t)f * 1024 + j];
#pragma unroll
            for (int r = 0; r < 8; ++r) acc[r] += a[r][f] * w;
        }
        for (int r = 0; r < 8; ++r) Wc[(size_t)(r0 + r) * 1024 + j] = (__bf16)acc[r];
    }
}

// decoder pack: 32 cols/WG {r:Whh+Wc, z:Whh+Wc, n_i:Wc, n_h:Whh}
__global__ void k_pack_dec(const float* __restrict__ Whhd, const __bf16* __restrict__ Wc,
                           const float* __restrict__ Wihd,
                           const float* __restrict__ bihd, const float* __restrict__ bhhd,
                           const float* __restrict__ bout,
                           __bf16* __restrict__ Wd, float* __restrict__ bd) {
    int g = blockIdx.x, tid = threadIdx.x;
    for (int i = tid; i < 32 * 1024; i += 256) {
        int c = i >> 10, k = i & 1023;
        int u = g * U_ + (c >> 2), gate = c & 3;
        float v;
        if (gate == 0)      v = Whhd[(size_t)u * 1024 + k] + (float)Wc[(size_t)u * 1024 + k];
        else if (gate == 1) v = Whhd[(size_t)(1024 + u) * 1024 + k] + (float)Wc[(size_t)(1024 + u) * 1024 + k];
        else if (gate == 2) v = (float)Wc[(size_t)(2048 + u) * 1024 + k];
        else                v = Whhd[(size_t)(2048 + u) * 1024 + k];
        Wd[((size_t)g * 32 + c) * 1024 + k] = (__bf16)v;
    }
    if (tid < 32) {
        int c = tid;
        int u = g * U_ + (c >> 2), gate = c & 3;
        int row = (gate == 0) ? u : (gate == 1) ? (1024 + u) : (2048 + u);
        float v;
        if (gate <= 1) {
            float d = 0.f;
            for (int f = 0; f < 128; ++f) d += Wihd[(size_t)row * 128 + f] * bout[f];
            v = d + bihd[row] + bhhd[row];
        } else if (gate == 2) {
            float d = 0.f;
            for (int f = 0; f < 128; ++f) d += Wihd[(size_t)row * 128 + f] * bout[f];
            v = d + bihd[row];
        } else {
            v = bhhd[row];
        }
        bd[g * 32 + c] = v;
    }
}

// ---------------- barrier: 16 counters (128B apart), single-hop all-poll, NO inv ----------

__device__ __forceinline__ void bar_arrive(unsigned* base, int g) {
    if (threadIdx.x == 0)
        __hip_atomic_fetch_add(base + (g & 15) * 32, 1u,
                               __ATOMIC_RELAXED, __HIP_MEMORY_SCOPE_AGENT);
}

__device__ __forceinline__ void bar_wait(unsigned* base, unsigned tgt) {
    if (threadIdx.x == 0) {
        for (;;) {
            unsigned sum = 0;
#pragma unroll
            for (int j = 0; j < 16; ++j)
                sum += __hip_atomic_load(base + j * 32, __ATOMIC_RELAXED, __HIP_MEMORY_SCOPE_AGENT);
            if (sum >= tgt) break;
            __builtin_amdgcn_s_sleep(1);
        }
    }
    __syncthreads();
}

// ---------------- encoder ----------------
// 8 GEMM waves: wave w (w<4) rows (w&3)*32, K-frags 0..31 -> sGa;
//               wave w+4     same rows,     K-frags 32..63 -> sGb (+ x part, overlapped).
__global__ __launch_bounds__(512, 2) void k_enc(
    const __bf16* __restrict__ xb, const __bf16* __restrict__ Weh,
    const __bf16* __restrict__ Wex, const float* __restrict__ be,
    __bf16* __restrict__ h0, __bf16* __restrict__ h1,
    float* __restrict__ h32, unsigned* __restrict__ ctr) {
    __shared__ __align__(16) __bf16 sWh[32][1032];
    __shared__ __align__(16) __bf16 sWx[32][136];
    __shared__ float sB[32];
    __shared__ __align__(16) float sGa[128][36];
    __shared__ __align__(16) float sGb[128][36];
    const int g = blockIdx.x, tid = threadIdx.x;
    const int lane = tid & 63, wave = tid >> 6;

    for (int i = tid; i < 32 * 128; i += 512) {
        int c = i >> 7, k8 = i & 127;
        *(i32x4*)&sWh[c][k8 * 8] = *(const i32x4*)(Weh + ((size_t)g * 32 + c) * 1024 + k8 * 8);
    }
    for (int i = tid; i < 32 * 16; i += 512) {
        int c = i >> 4, k8 = i & 15;
        *(i32x4*)&sWx[c][k8 * 8] = *(const i32x4*)(Wex + ((size_t)g * 32 + c) * 128 + k8 * 8);
    }
    if (tid < 32) sB[tid] = be[g * 32 + tid];
    __syncthreads();

    const int bcol = lane & 31;
    const int koff = (lane >> 5) * 8;
    const int mrow = (wave & 3) * 32 + bcol;
    const int kb = (wave >> 2) * 32;           // this wave's K-frag base
    const bool up = (wave >= 4);

    bf16x8 xrg[8];
    if (up) {
#pragma unroll
        for (int kt = 0; kt < 8; ++kt) xrg[kt] = *(const bf16x8*)(&sWx[bcol][kt * 16 + koff]);
    }

    const int erow = tid >> 2, pair = tid & 3;
    // transposed h: u32 index = kgroup*512 + row*4 + pair; this WG's kgroup = g
    const int hidx2 = g * 512 + erow * 4 + pair;
    float ha = 0.f, hb = 0.f;

    // x-part of step 0 (upper waves)
    f32x16 accx = Z16;
    if (up) {
        const __bf16* xr = xb + (size_t)mrow * 65536;
#pragma unroll
        for (int kt = 0; kt < 8; ++kt)
            accx = MFMA32(*(const bf16x8*)(xr + kt * 16 + koff), xrg[kt], accx);
    }

    for (int s = 0; s < 512; ++s) {
        const __bf16* hcur = (s & 1) ? h1 : h0;
        __bf16* hnxt = (s & 1) ? h0 : h1;
        {
            f32x16 aA = up ? accx : Z16;
            f32x16 aB = Z16;
            // transposed h read: frag i (cols (kb+i)*16+koff .. +7) = 16B at
            // [kgroup=(kb+i)*2+(koff>>3)][row=mrow][0..7]; stride per i = 2048 elems (4KB)
            const __bf16* hr = hcur + ((size_t)(kb * 2 + (koff >> 3)) << 10) + mrow * 8;
            bf16x8 af[16];
#pragma unroll
            for (int i = 0; i < 16; ++i) LDG16(af[i], hr + i * 2048);
            VMWAIT16(af); SB0();
#pragma unroll
            for (int i = 0; i < 16; ++i) {
                const bf16x8 b = *(const bf16x8*)(&sWh[bcol][(kb + i) * 16 + koff]);
                if (i & 1) aB = MFMA32(af[i], b, aB); else aA = MFMA32(af[i], b, aA);
                LDG16(af[i], hr + (16 + i) * 2048);
            }
            VMWAIT16(af); SB0();
#pragma unroll
            for (int i = 0; i < 16; ++i) {
                const bf16x8 b = *(const bf16x8*)(&sWh[bcol][(kb + 16 + i) * 16 + koff]);
                if (i & 1) aB = MFMA32(af[i], b, aB); else aA = MFMA32(af[i], b, aA);
            }
            f32x16 acc = aA + aB;
            // C frag: col = lane&31, row = (r&3) + 8*(r>>2) + 4*(lane>>5)
            int rb = (wave & 3) * 32 + 4 * (lane >> 5);
            float (*sg)[36] = up ? sGb : sGa;
#pragma unroll
            for (int r = 0; r < 16; ++r)
                sg[rb + (r & 3) + 8 * (r >> 2)][bcol] = acc[r];
        }
        __syncthreads();
        {
            f32x4 g0 = *(const f32x4*)&sGa[erow][pair * 8] + *(const f32x4*)&sGb[erow][pair * 8];
            f32x4 g1 = *(const f32x4*)&sGa[erow][pair * 8 + 4] + *(const f32x4*)&sGb[erow][pair * 8 + 4];
            int c0 = pair * 8;
            float r = 1.f / (1.f + __expf(-(g0[0] + sB[c0 + 0])));
            float z = 1.f / (1.f + __expf(-(g0[1] + sB[c0 + 1])));
            float n = tanhf(g0[2] + sB[c0 + 2] + r * (g0[3] + sB[c0 + 3]));
            ha = (1.f - z) * n + z * ha;
            r = 1.f / (1.f + __expf(-(g1[0] + sB[c0 + 4])));
            z = 1.f / (1.f + __expf(-(g1[1] + sB[c0 + 5])));
            n = tanhf(g1[2] + sB[c0 + 6] + r * (g1[3] + sB[c0 + 7]));
            hb = (1.f - z) * n + z * hb;
            pk2 p; p.h[0] = (__bf16)ha; p.h[1] = (__bf16)hb;
            __hip_atomic_store((unsigned*)hnxt + hidx2, p.u, __ATOMIC_RELAXED, __HIP_MEMORY_SCOPE_AGENT);
            if (s == 511) {
                h32[erow * 1024 + g * 8 + pair * 2]     = ha;
                h32[erow * 1024 + g * 8 + pair * 2 + 1] = hb;
            }
        }
        if (s < 511) {
            __syncthreads();              // drains write-through h stores (vmcnt 0)
            bar_arrive(ctr, g);
            // overlap: x-part of step s+1 (x read-only, cached — L2 stays warm, no inv ever)
            if (up) {
                f32x16 ax = Z16;
                const __bf16* xr = xb + (size_t)mrow * 65536 + (size_t)(s + 1) * 128;
#pragma unroll
                for (int kt = 0; kt < 8; ++kt)
                    ax = MFMA32(*(const bf16x8*)(xr + kt * 16 + koff), xrg[kt], ax);
                accx = ax;
            }
            bar_wait(ctr, (unsigned)(s + 1) * NWG_E);
        }
    }
}

// ---------------- decoder ----------------
// g < 128  : gate WG (32 gate cols; 8 K-split GEMM waves; all waves gate math)
// g >= 128 : out WG  (one 32x32 out tile; 4-wave K-split partials -> LDS reduce -> store)
__global__ __launch_bounds__(512, 2) void k_dec(
    const __bf16* __restrict__ Wd, const float* __restrict__ bd,
    const __bf16* __restrict__ Wob, const float* __restrict__ bout,
    __bf16* __restrict__ h0, __bf16* __restrict__ h1,
    const float* __restrict__ h32, float* __restrict__ out,
    unsigned* __restrict__ ctr) {
    __shared__ __align__(16) __bf16 sW[32][1032];
    __shared__ float sB[32];
    __shared__ __align__(16) float sGa[128][36];
    __shared__ __align__(16) float sGb[128][36];
    const int g = blockIdx.x, tid = threadIdx.x;
    const int lane = tid & 63, wave = tid >> 6;
    const bool gwg = (g < 128);
    const int go = g - 128;

    if (gwg) {
        for (int i = tid; i < 32 * 128; i += 512) {
            int c = i >> 7, k8 = i & 127;
            *(i32x4*)&sW[c][k8 * 8] = *(const i32x4*)(Wd + ((size_t)g * 32 + c) * 1024 + k8 * 8);
        }
        if (tid < 32) sB[tid] = bd[g * 32 + tid];
    } else {
        for (int i = tid; i < 32 * 128; i += 512) {
            int c = i >> 7, k8 = i & 127;
            *(i32x4*)&sW[c][k8 * 8] =
                *(const i32x4*)(Wob + ((size_t)((go >> 2) * 32 + c)) * 1024 + k8 * 8);
        }
        if (tid < 32) sB[tid] = bout[(go >> 2) * 32 + tid];
    }
    __syncthreads();

    const int bcol = lane & 31;
    const int koff = (lane >> 5) * 8;
    const int kb = (wave >> 2) * 32;
    const bool up = (wave >= 4);
    const int arow = gwg ? ((wave & 3) * 32 + bcol)   // batch row, gate gemm
                         : ((go & 3) * 32 + bcol);    // batch row, out gemm

    const int erow = tid >> 2, pair = tid & 3;
    const int hidx2 = g * 512 + erow * 4 + pair;      // transposed h store index (gate WGs)
    float ha = 0.f, hb = 0.f;
    if (gwg) {
        ha = h32[erow * 1024 + g * 8 + pair * 2];
        hb = h32[erow * 1024 + g * 8 + pair * 2 + 1];
    }

    if (gwg) {
        for (int s = 0; s < 512; ++s) {
            const __bf16* hcur = (s & 1) ? h1 : h0;
            __bf16* hnxt = (s & 1) ? h0 : h1;
            {
                f32x16 aA = Z16, aB = Z16;
                const __bf16* hr = hcur + ((size_t)(kb * 2 + (koff >> 3)) << 10) + arow * 8;
                bf16x8 af[16];
#pragma unroll
                for (int i = 0; i < 16; ++i) LDG16(af[i], hr + i * 2048);
                VMWAIT16(af); SB0();
#pragma unroll
                for (int i = 0; i < 16; ++i) {
                    const bf16x8 b = *(const bf16x8*)(&sW[bcol][(kb + i) * 16 + koff]);
                    if (i & 1) aB = MFMA32(af[i], b, aB); else aA = MFMA32(af[i], b, aA);
                    LDG16(af[i], hr + (16 + i) * 2048);
                }
                VMWAIT16(af); SB0();
#pragma unroll
                for (int i = 0; i < 16; ++i) {
                    const bf16x8 b = *(const bf16x8*)(&sW[bcol][(kb + 16 + i) * 16 + koff]);
                    if (i & 1) aB = MFMA32(af[i], b, aB); else aA = MFMA32(af[i], b, aA);
                }
                f32x16 acc = aA + aB;
                int rb = (wave & 3) * 32 + 4 * (lane >> 5);
                float (*sg)[36] = up ? sGb : sGa;
#pragma unroll
                for (int r = 0; r < 16; ++r)
                    sg[rb + (r & 3) + 8 * (r >> 2)][bcol] = acc[r];
            }
            __syncthreads();
            {
                f32x4 g0 = *(const f32x4*)&sGa[erow][pair * 8] + *(const f32x4*)&sGb[erow][pair * 8];
                f32x4 g1 = *(const f32x4*)&sGa[erow][pair * 8 + 4] + *(const f32x4*)&sGb[erow][pair * 8 + 4];
                int c0 = pair * 8;
                float r = 1.f / (1.f + __expf(-(g0[0] + sB[c0 + 0])));
                float z = 1.f / (1.f + __expf(-(g0[1] + sB[c0 + 1])));
                float n = tanhf(g0[2] + sB[c0 + 2] + r * (g0[3] + sB[c0 + 3]));
                ha = (1.f - z) * n + z * ha;
                r = 1.f / (1.f + __expf(-(g1[0] + sB[c0 + 4])));
                z = 1.f / (1.f + __expf(-(g1[1] + sB[c0 + 5])));
                n = tanhf(g1[2] + sB[c0 + 6] + r * (g1[3] + sB[c0 + 7]));
                hb = (1.f - z) * n + z * hb;
                pk2 p; p.h[0] = (__bf16)ha; p.h[1] = (__bf16)hb;
                __hip_atomic_store((unsigned*)hnxt + hidx2, p.u, __ATOMIC_RELAXED, __HIP_MEMORY_SCOPE_AGENT);
            }
            __syncthreads();              // drains write-through h stores
            bar_arrive(ctr, g);
            if (s < 511) bar_wait(ctr, (unsigned)(s + 1) * NWG_D);
        }
    } else {
        // out WG: iteration s computes out col 512-s = h_s @ W_out^T + b (s = 1..512).
        // 4 GEMM waves, each a K-quarter (16 frags) of the same 32x32 tile; partials in
        // sGo; all 512 threads reduce + store (overlapped with the barrier poll window).
        __shared__ __align__(16) float sGo[4][32][32];
        for (int s = 0; s <= 512; ++s) {
            const __bf16* hcur = (s & 1) ? h1 : h0;
            const bool cmp = (wave < 4) && (s >= 1);
            if (cmp) {
                f32x16 aA = Z16, aB = Z16;
                const __bf16* hr = hcur + ((size_t)(wave * 32 + (koff >> 3)) << 10) + arow * 8;
                bf16x8 af[16];
#pragma unroll
                for (int i = 0; i < 16; ++i) LDG16(af[i], hr + i * 2048);
                VMWAIT16(af); SB0();
#pragma unroll
                for (int i = 0; i < 16; ++i) {
                    const bf16x8 b = *(const bf16x8*)(&sW[bcol][(wave * 16 + i) * 16 + koff]);
                    if (i & 1) aB = MFMA32(af[i], b, aB); else aA = MFMA32(af[i], b, aA);
                }
                f32x16 acc = aA + aB;
                int rb = 4 * (lane >> 5);
#pragma unroll
                for (int r = 0; r < 16; ++r)
                    sGo[wave][rb + (r & 3) + 8 * (r >> 2)][bcol] = acc[r];
            }
            __syncthreads();              // h consumed into regs/partials; sGo visible
            if (s < 512) bar_arrive(ctr, g);
            if (s >= 1) {
                // reduce 4 partials, add bias, store 2 elements per thread
                int c = tid & 31, r0 = (tid >> 5) & 15;
#pragma unroll
                for (int hh = 0; hh < 2; ++hh) {
                    int r = r0 + hh * 16;
                    fu cv;
                    cv.f = sGo[0][r][c] + sGo[1][r][c] + sGo[2][r][c] + sGo[3][r][c] + sB[c];
                    size_t off = ((size_t)((go & 3) * 32 + r) * 512 + (size_t)(512 - s)) * 128
                               + (go >> 2) * 32 + c;
                    __hip_atomic_store((unsigned*)(out + off), cv.u,
                                       __ATOMIC_RELAXED, __HIP_MEMORY_SCOPE_AGENT);
                }
            }
            if (s < 512) bar_wait(ctr, (unsigned)(s + 1) * NWG_D);
        }
    }
}

// ---------------- launch ----------------
extern "C" void kernel_launch(void* const* d_in, const int* in_sizes, int n_in,
                              void* d_out, int out_size, void* d_ws, size_t ws_size,
                              hipStream_t stream) {
    (void)in_sizes; (void)n_in; (void)out_size; (void)ws_size;
    const float* x    = (const float*)d_in[0];
    const float* Wihe = (const float*)d_in[1];
    const float* Whhe = (const float*)d_in[2];
    const float* bihe = (const float*)d_in[3];
    const float* bhhe = (const float*)d_in[4];
    const float* Wihd = (const float*)d_in[5];
    const float* Whhd = (const float*)d_in[6];
    const float* bihd = (const float*)d_in[7];
    const float* bhhd = (const float*)d_in[8];
    const float* Wout = (const float*)d_in[9];
    const float* bout = (const float*)d_in[10];

    char* ws = (char*)d_ws;
    __bf16*   h0  = (__bf16*)(ws + O_H0);
    __bf16*   h1  = (__bf16*)(ws + O_H1);
    float*    h32 = (float*)(ws + O_H32);
    unsigned* ctr = (unsigned*)(ws + O_CTR);
    __bf16*   xbf = (__bf16*)(ws + O_XB);
    __bf16*   Weh = (__bf16*)(ws + O_WEH);
    __bf16*   Wex = (__bf16*)(ws + O_WEX);
    float*    be  = (float*)(ws + O_BE);
    __bf16*   Wd  = (__bf16*)(ws + O_WD);
    float*    bd  = (float*)(ws + O_BD);
    __bf16*   Wc  = (__bf16*)(ws + O_WC);
    __bf16*   Wob = (__bf16*)(ws + O_WOB);

    hipMemsetAsync(ws, 0, O_ZERO_END, stream);   // h0/h1/h32 + both sync blocks

    k_xcvt<<<4096, 256, 0, stream>>>(x, xbf, B_ * S_ * F_);
    k_pack_enc<<<NWG_E, 256, 0, stream>>>(Wihe, Whhe, bihe, bhhe, Weh, Wex, be);
    k_wcomb<<<384, 256, 0, stream>>>(Wihd, Wout, Wc);
    k_pack_dec<<<NWG_E, 256, 0, stream>>>(Whhd, Wc, Wihd, bihd, bhhd, bout, Wd, bd);
    k_woutb<<<512, 256, 0, stream>>>(Wout, Wob, F_ * L_);

    k_enc<<<NWG_E, 512, 0, stream>>>(xbf, Weh, Wex, be, h0, h1, h32, ctr);
    k_dec<<<NWG_D, 512, 0, stream>>>(Wd, bd, Wob, bout, h0, h1, h32, (float*)d_out,
                                     ctr + 1024);
}